// Round 1
// baseline (1455.865 us; speedup 1.0000x reference)
//
#include <hip/hip_runtime.h>

// Problem constants
#define B_ 8
#define T_ 4096
#define D_ 768
#define NH_ 12
#define HD_ 64
#define M_ 64            // N_STATE
#define ALPHA_ 0.1f

// Chunking: T split into 8 chunks of 512; each chunk processed as 4 sub-tiles of 128.
#define CCH 8
#define CHUNK_T 512
#define SUB_T 128
#define NSUB 4

// ws layout in floats
#define P_OFF   0
#define P_SIZE  (NH_*M_*D_)                 // 589824  (P[h][m][e])
#define CP_OFF  (P_OFF + P_SIZE)
#define CP_SIZE (B_*NH_*CCH*M_)             // 49152   (chunk gate products)
#define PT_OFF  (CP_OFF + CP_SIZE)
#define PT_SIZE (B_*NH_*CCH*M_*HD_)         // 3145728 (per-chunk partial s)

// ---------------------------------------------------------------------------
// Kernel 0: P[h,m,e] = sum_i proto[m, h*64+i] * W[h*64+i, e]
// grid (6 e-tiles of 128, 12 heads), 256 threads
// ---------------------------------------------------------------------------
__global__ __launch_bounds__(256) void kP(const float* __restrict__ proto,
                                          const float* __restrict__ W,
                                          float* __restrict__ P) {
    const int et = blockIdx.x;   // 0..5
    const int h  = blockIdx.y;   // 0..11
    const int tid = threadIdx.x;

    __shared__ __align__(16) float Ws[64 * 128];  // Ws[i][e]
    __shared__ __align__(16) float Ks[64 * 64];   // Ks[i][m] = proto[m][h*64+i]

    // stage W slice: rows h*64+i, cols et*128..+127  (2048 float4, 8/thread)
#pragma unroll
    for (int j = 0; j < 8; ++j) {
        int f = tid + j * 256;
        int i = f >> 5, c4 = f & 31;
        const float4 v = *reinterpret_cast<const float4*>(
            W + (size_t)(h * 64 + i) * D_ + et * 128 + c4 * 4);
        *reinterpret_cast<float4*>(&Ws[i * 128 + c4 * 4]) = v;
    }
    // stage proto slice transposed (1024 float4, 4/thread)
#pragma unroll
    for (int j = 0; j < 4; ++j) {
        int f = tid + j * 256;
        int m = f >> 4, i4 = f & 15;
        const float4 v = *reinterpret_cast<const float4*>(
            proto + (size_t)m * D_ + h * 64 + i4 * 4);
        Ks[(i4 * 4 + 0) * 64 + m] = v.x;
        Ks[(i4 * 4 + 1) * 64 + m] = v.y;
        Ks[(i4 * 4 + 2) * 64 + m] = v.z;
        Ks[(i4 * 4 + 3) * 64 + m] = v.w;
    }
    __syncthreads();

    const int m0 = (tid >> 5) * 8;   // 8 m per thread
    const int e0 = (tid & 31) * 4;   // 4 e per thread
    float acc[8][4];
#pragma unroll
    for (int i = 0; i < 8; ++i)
#pragma unroll
        for (int j = 0; j < 4; ++j) acc[i][j] = 0.f;

    for (int i = 0; i < 64; ++i) {
        const float4 bb = *reinterpret_cast<const float4*>(&Ws[i * 128 + e0]);
        const float4 a0 = *reinterpret_cast<const float4*>(&Ks[i * 64 + m0]);
        const float4 a1 = *reinterpret_cast<const float4*>(&Ks[i * 64 + m0 + 4]);
        const float a[8] = {a0.x, a0.y, a0.z, a0.w, a1.x, a1.y, a1.z, a1.w};
#pragma unroll
        for (int mi = 0; mi < 8; ++mi) {
            acc[mi][0] = fmaf(a[mi], bb.x, acc[mi][0]);
            acc[mi][1] = fmaf(a[mi], bb.y, acc[mi][1]);
            acc[mi][2] = fmaf(a[mi], bb.z, acc[mi][2]);
            acc[mi][3] = fmaf(a[mi], bb.w, acc[mi][3]);
        }
    }
#pragma unroll
    for (int mi = 0; mi < 8; ++mi) {
        float4 v = make_float4(acc[mi][0], acc[mi][1], acc[mi][2], acc[mi][3]);
        *reinterpret_cast<float4*>(
            P + (size_t)(h * 64 + m0 + mi) * D_ + et * 128 + e0) = v;
    }
}

// ---------------------------------------------------------------------------
// Kernel 1: per (chunk c, head h, batch b): fused score-GEMM + softmax +
// backward gate scan + partial accumulation.
// grid (8, 12, 8), 256 threads. LDS ~59 KB -> 2 blocks/CU.
// ---------------------------------------------------------------------------
__global__ __launch_bounds__(256) void k1(const float* __restrict__ H,
                                          const float* __restrict__ P,
                                          float* __restrict__ chunkprod,
                                          float* __restrict__ partial) {
    const int c   = blockIdx.x;   // chunk 0..7
    const int h   = blockIdx.y;   // head  0..11
    const int b   = blockIdx.z;   // batch 0..7
    const int tid = threadIdx.x;

    __shared__ __align__(16) float sc[SUB_T * 65];           // scores/w_eff, stride 65
    __shared__ __align__(16) float stage[32 * 132 + 32 * 68]; // Hs | Ps ; aliased by Hh
    __shared__ float inv_sum[SUB_T];
    float* Hs = stage;             // [32 k][132] (t-major, padded)
    float* Ps = stage + 32 * 132;  // [32 k][68]  (m-major, padded)
    float* Hh = stage;             // [64 t][68]  (alias, partial phase)

    const int t_chunk = c * CHUNK_T;

    // partial accumulator: 64m x 64d over 256 threads -> 4m x 4d per thread
    const int pm0 = (tid >> 4) * 4;
    const int pd0 = (tid & 15) * 4;
    float pacc[4][4];
#pragma unroll
    for (int i = 0; i < 4; ++i)
#pragma unroll
        for (int j = 0; j < 4; ++j) pacc[i][j] = 0.f;

    float running = 1.0f;  // gate suffix product (live in tid<64)

    // score tile: 128t x 64m over 256 threads -> 8t x 4m per thread
    const int sg_t0 = (tid >> 4) * 8;
    const int sg_m0 = (tid & 15) * 4;

    for (int s = NSUB - 1; s >= 0; --s) {   // reverse order: suffix scan carries
        const int t_sub = t_chunk + s * SUB_T;

        // ---- score GEMM: sc[t][m] = (1/8) * H[t,:] . P[h,m,:] ----
        float acc[8][4];
#pragma unroll
        for (int i = 0; i < 8; ++i)
#pragma unroll
            for (int j = 0; j < 4; ++j) acc[i][j] = 0.f;

        for (int kt = 0; kt < D_ / 32; ++kt) {
            __syncthreads();
            // stage Hs (transpose to [k][t]): 1024 float4, 4/thread
#pragma unroll
            for (int j = 0; j < 4; ++j) {
                int f = tid + j * 256;
                int t = f >> 3, k4 = f & 7;
                const float4 v = *reinterpret_cast<const float4*>(
                    H + (size_t)(b * T_ + t_sub + t) * D_ + kt * 32 + k4 * 4);
                Hs[(k4 * 4 + 0) * 132 + t] = v.x;
                Hs[(k4 * 4 + 1) * 132 + t] = v.y;
                Hs[(k4 * 4 + 2) * 132 + t] = v.z;
                Hs[(k4 * 4 + 3) * 132 + t] = v.w;
            }
            // stage Ps (transpose to [k][m]): 512 float4, 2/thread
#pragma unroll
            for (int j = 0; j < 2; ++j) {
                int f = tid + j * 256;
                int m = f >> 3, k4 = f & 7;
                const float4 v = *reinterpret_cast<const float4*>(
                    P + (size_t)(h * 64 + m) * D_ + kt * 32 + k4 * 4);
                Ps[(k4 * 4 + 0) * 68 + m] = v.x;
                Ps[(k4 * 4 + 1) * 68 + m] = v.y;
                Ps[(k4 * 4 + 2) * 68 + m] = v.z;
                Ps[(k4 * 4 + 3) * 68 + m] = v.w;
            }
            __syncthreads();
#pragma unroll
            for (int k = 0; k < 32; ++k) {
                const float4 a0 = *reinterpret_cast<const float4*>(&Hs[k * 132 + sg_t0]);
                const float4 a1 = *reinterpret_cast<const float4*>(&Hs[k * 132 + sg_t0 + 4]);
                const float4 bb = *reinterpret_cast<const float4*>(&Ps[k * 68 + sg_m0]);
                const float a[8] = {a0.x, a0.y, a0.z, a0.w, a1.x, a1.y, a1.z, a1.w};
#pragma unroll
                for (int i = 0; i < 8; ++i) {
                    acc[i][0] = fmaf(a[i], bb.x, acc[i][0]);
                    acc[i][1] = fmaf(a[i], bb.y, acc[i][1]);
                    acc[i][2] = fmaf(a[i], bb.z, acc[i][2]);
                    acc[i][3] = fmaf(a[i], bb.w, acc[i][3]);
                }
            }
        }
        __syncthreads();
#pragma unroll
        for (int i = 0; i < 8; ++i)
#pragma unroll
            for (int j = 0; j < 4; ++j)
                sc[(sg_t0 + i) * 65 + sg_m0 + j] = acc[i][j] * 0.125f;
        __syncthreads();

        // ---- softmax over m per row (store unnormalized exp + 1/sum) ----
        if (tid < SUB_T) {
            const int base = tid * 65;
            float mx = sc[base];
            for (int m = 1; m < M_; ++m) mx = fmaxf(mx, sc[base + m]);
            float sum = 0.f;
            for (int m = 0; m < M_; ++m) {
                const float e = __expf(sc[base + m] - mx);
                sc[base + m] = e;
                sum += e;
            }
            inv_sum[tid] = 1.0f / sum;
        }
        __syncthreads();

        // ---- backward gate scan (tid<64 owns column m) ----
        if (tid < M_) {
            const int m = tid;
            for (int t = SUB_T - 1; t >= 0; --t) {
                const float w = sc[t * 65 + m] * inv_sum[t];
                sc[t * 65 + m] = ALPHA_ * w * running;          // w_eff
                running *= (1.0f - ALPHA_ * w);                  // g
            }
        }
        __syncthreads();

        // ---- partial accumulation: pacc[m][d] += sum_t w_eff[t,m]*H[t, h*64+d] ----
        for (int hh = 0; hh < 2; ++hh) {
            __syncthreads();  // previous Hh readers done
#pragma unroll
            for (int j = 0; j < 4; ++j) {
                int f = tid + j * 256;
                int t = f >> 4, d4 = f & 15;
                const float4 v = *reinterpret_cast<const float4*>(
                    H + (size_t)(b * T_ + t_sub + hh * 64 + t) * D_ + h * 64 + d4 * 4);
                *reinterpret_cast<float4*>(&Hh[t * 68 + d4 * 4]) = v;
            }
            __syncthreads();
#pragma unroll 8
            for (int t = 0; t < 64; ++t) {
                const int r = hh * 64 + t;
                const float4 bb = *reinterpret_cast<const float4*>(&Hh[t * 68 + pd0]);
                const float a0 = sc[r * 65 + pm0 + 0];
                const float a1 = sc[r * 65 + pm0 + 1];
                const float a2 = sc[r * 65 + pm0 + 2];
                const float a3 = sc[r * 65 + pm0 + 3];
                pacc[0][0] = fmaf(a0, bb.x, pacc[0][0]); pacc[0][1] = fmaf(a0, bb.y, pacc[0][1]);
                pacc[0][2] = fmaf(a0, bb.z, pacc[0][2]); pacc[0][3] = fmaf(a0, bb.w, pacc[0][3]);
                pacc[1][0] = fmaf(a1, bb.x, pacc[1][0]); pacc[1][1] = fmaf(a1, bb.y, pacc[1][1]);
                pacc[1][2] = fmaf(a1, bb.z, pacc[1][2]); pacc[1][3] = fmaf(a1, bb.w, pacc[1][3]);
                pacc[2][0] = fmaf(a2, bb.x, pacc[2][0]); pacc[2][1] = fmaf(a2, bb.y, pacc[2][1]);
                pacc[2][2] = fmaf(a2, bb.z, pacc[2][2]); pacc[2][3] = fmaf(a2, bb.w, pacc[2][3]);
                pacc[3][0] = fmaf(a3, bb.x, pacc[3][0]); pacc[3][1] = fmaf(a3, bb.y, pacc[3][1]);
                pacc[3][2] = fmaf(a3, bb.z, pacc[3][2]); pacc[3][3] = fmaf(a3, bb.w, pacc[3][3]);
            }
        }
        __syncthreads();  // Hh (alias of Hs/Ps) free before next sub-tile stages
    }

    const int chunkIdx = (b * NH_ + h) * CCH + c;
    if (tid < M_) chunkprod[chunkIdx * M_ + tid] = running;
#pragma unroll
    for (int i = 0; i < 4; ++i) {
        float4 v = make_float4(pacc[i][0], pacc[i][1], pacc[i][2], pacc[i][3]);
        *reinterpret_cast<float4*>(
            partial + ((size_t)chunkIdx * M_ + pm0 + i) * HD_ + pd0) = v;
    }
}

// ---------------------------------------------------------------------------
// Kernel 2: combine chunks with cross-chunk suffix gate products + s0 term.
// grid (12 heads, 8 batch), 256 threads.
// ---------------------------------------------------------------------------
__global__ __launch_bounds__(256) void k2(const float* __restrict__ chunkprod,
                                          const float* __restrict__ partial,
                                          const float* __restrict__ s0,
                                          float* __restrict__ out) {
    const int h = blockIdx.x;
    const int b = blockIdx.y;
    const int tid = threadIdx.x;

    __shared__ float Sfx[CCH * M_];
    __shared__ float tot[M_];

    if (tid < M_) {
        const int m = tid;
        float run = 1.0f;
        for (int c = CCH - 1; c >= 0; --c) {
            Sfx[c * M_ + m] = run;  // product over chunks > c
            run *= chunkprod[((size_t)(b * NH_ + h) * CCH + c) * M_ + m];
        }
        tot[m] = run;               // product over all chunks
    }
    __syncthreads();

    const int m  = tid >> 2;
    const int d0 = (tid & 3) * 16;
    const float tm = tot[m];
    float4 acc[4];
#pragma unroll
    for (int q = 0; q < 4; ++q) {
        const float4 v = *reinterpret_cast<const float4*>(
            s0 + (size_t)m * D_ + h * 64 + d0 + q * 4);
        acc[q] = make_float4(v.x * tm, v.y * tm, v.z * tm, v.w * tm);
    }
    for (int c = 0; c < CCH; ++c) {
        const float sv = Sfx[c * M_ + m];
        const size_t base = (((size_t)(b * NH_ + h) * CCH + c) * M_ + m) * HD_ + d0;
#pragma unroll
        for (int q = 0; q < 4; ++q) {
            const float4 p = *reinterpret_cast<const float4*>(partial + base + q * 4);
            acc[q].x = fmaf(sv, p.x, acc[q].x);
            acc[q].y = fmaf(sv, p.y, acc[q].y);
            acc[q].z = fmaf(sv, p.z, acc[q].z);
            acc[q].w = fmaf(sv, p.w, acc[q].w);
        }
    }
    const size_t ob = (size_t)(b * M_ + m) * D_ + h * 64 + d0;
#pragma unroll
    for (int q = 0; q < 4; ++q)
        *reinterpret_cast<float4*>(out + ob + q * 4) = acc[q];
}

// ---------------------------------------------------------------------------
extern "C" void kernel_launch(void* const* d_in, const int* in_sizes, int n_in,
                              void* d_out, int out_size, void* d_ws, size_t ws_size,
                              hipStream_t stream) {
    const float* H     = (const float*)d_in[0];  // [8,4096,768]
    const float* proto = (const float*)d_in[1];  // [64,768]
    const float* W     = (const float*)d_in[2];  // [768,768]
    const float* s0    = (const float*)d_in[3];  // [1,64,768]
    float* out = (float*)d_out;                  // [8,64,768]

    float* wsf       = (float*)d_ws;
    float* P         = wsf + P_OFF;
    float* chunkprod = wsf + CP_OFF;
    float* partial   = wsf + PT_OFF;

    kP<<<dim3(6, NH_), 256, 0, stream>>>(proto, W, P);
    k1<<<dim3(CCH, NH_, B_), 256, 0, stream>>>(H, P, chunkprod, partial);
    k2<<<dim3(NH_, B_), 256, 0, stream>>>(chunkprod, partial, s0, out);
}

// Round 2
// 370.342 us; speedup vs baseline: 3.9311x; 3.9311x over previous
//
#include <hip/hip_runtime.h>

#define B_ 8
#define T_ 4096
#define D_ 768
#define NH_ 12
#define HD_ 64
#define M_ 64
#define ALPHA_ 0.1f

#define CCH 8        // chunks over T
#define CHUNK_T 512
#define SUB_T 256    // subtile
#define NSUB 2

typedef __attribute__((ext_vector_type(8))) short short8;     // 8 bf16 = 4 VGPRs
typedef __attribute__((ext_vector_type(16))) float f32x16;
typedef __attribute__((ext_vector_type(4))) float f32x4;

// ws layout (see kernel_launch): P_hi/P_lo ushort[12*64*768], chunkprod f32, partial f32

__device__ __forceinline__ unsigned int rtne_bf16(float x) {
    unsigned int u = __float_as_uint(x);
    return (u + 0x7FFFu + ((u >> 16) & 1u)) >> 16;
}
__device__ __forceinline__ float bf16_to_f(unsigned int h) {
    return __uint_as_float(h << 16);
}

// ---------------------------------------------------------------------------
// Kernel 0: P[h,m,e] = (1/8) * sum_i proto[m, h*64+i] * W[h*64+i, e], split
// into bf16 hi/lo (truncation split: hi = trunc16(v), lo = bf16(v - hi)).
// grid (6 e-tiles of 128, 12 heads), 256 threads
// ---------------------------------------------------------------------------
__global__ __launch_bounds__(256) void kP(const float* __restrict__ proto,
                                          const float* __restrict__ W,
                                          unsigned short* __restrict__ P_hi,
                                          unsigned short* __restrict__ P_lo) {
    const int et = blockIdx.x;
    const int h  = blockIdx.y;
    const int tid = threadIdx.x;

    __shared__ __align__(16) float Ws[64 * 128];
    __shared__ __align__(16) float Ks[64 * 64];

#pragma unroll
    for (int j = 0; j < 8; ++j) {
        int f = tid + j * 256;
        int i = f >> 5, c4 = f & 31;
        const float4 v = *reinterpret_cast<const float4*>(
            W + (size_t)(h * 64 + i) * D_ + et * 128 + c4 * 4);
        *reinterpret_cast<float4*>(&Ws[i * 128 + c4 * 4]) = v;
    }
#pragma unroll
    for (int j = 0; j < 4; ++j) {
        int f = tid + j * 256;
        int m = f >> 4, i4 = f & 15;
        const float4 v = *reinterpret_cast<const float4*>(
            proto + (size_t)m * D_ + h * 64 + i4 * 4);
        Ks[(i4 * 4 + 0) * 64 + m] = v.x;
        Ks[(i4 * 4 + 1) * 64 + m] = v.y;
        Ks[(i4 * 4 + 2) * 64 + m] = v.z;
        Ks[(i4 * 4 + 3) * 64 + m] = v.w;
    }
    __syncthreads();

    const int m0 = (tid >> 5) * 8;
    const int e0 = (tid & 31) * 4;
    float acc[8][4];
#pragma unroll
    for (int i = 0; i < 8; ++i)
#pragma unroll
        for (int j = 0; j < 4; ++j) acc[i][j] = 0.f;

    for (int i = 0; i < 64; ++i) {
        const float4 bb = *reinterpret_cast<const float4*>(&Ws[i * 128 + e0]);
        const float4 a0 = *reinterpret_cast<const float4*>(&Ks[i * 64 + m0]);
        const float4 a1 = *reinterpret_cast<const float4*>(&Ks[i * 64 + m0 + 4]);
        const float a[8] = {a0.x, a0.y, a0.z, a0.w, a1.x, a1.y, a1.z, a1.w};
#pragma unroll
        for (int mi = 0; mi < 8; ++mi) {
            acc[mi][0] = fmaf(a[mi], bb.x, acc[mi][0]);
            acc[mi][1] = fmaf(a[mi], bb.y, acc[mi][1]);
            acc[mi][2] = fmaf(a[mi], bb.z, acc[mi][2]);
            acc[mi][3] = fmaf(a[mi], bb.w, acc[mi][3]);
        }
    }
#pragma unroll
    for (int mi = 0; mi < 8; ++mi) {
        unsigned int hi16[4], lo16[4];
#pragma unroll
        for (int j = 0; j < 4; ++j) {
            float v = acc[mi][j] * 0.125f;
            unsigned int u = __float_as_uint(v);
            unsigned int hb = u & 0xFFFF0000u;
            float lo = v - __uint_as_float(hb);
            hi16[j] = u >> 16;
            lo16[j] = __float_as_uint(lo) >> 16;
        }
        size_t idx = (size_t)(h * 64 + m0 + mi) * D_ + et * 128 + e0;
        uint2 ph = {hi16[0] | (hi16[1] << 16), hi16[2] | (hi16[3] << 16)};
        uint2 pl = {lo16[0] | (lo16[1] << 16), lo16[2] | (lo16[3] << 16)};
        *reinterpret_cast<uint2*>(P_hi + idx) = ph;
        *reinterpret_cast<uint2*>(P_lo + idx) = pl;
    }
}

// ---------------------------------------------------------------------------
// Kernel 1: per (chunk, head, batch): MFMA score GEMM (hi/lo split) +
// in-register softmax + segmented suffix scan + MFMA partial accumulation.
// grid (8, 12, 8), 256 threads, dynamic LDS 52480 B.
//
// LDS map (bytes):
//   [0,20480)      sA_hi  u16[256][40]   (score phase)
//   [20480,40960)  sA_lo  u16[256][40]
//   [40960,46080)  sB_hi  u16[64][40]
//   [46080,51200)  sB_lo  u16[64][40]
//   [0,33792)      wT     u16[64][264]   (softmax/scan/partial; aliases sA)
//   [33792,50688)  Hh     u16[32][264]   (partial phase; aliases sA_lo/sB)
//   [51200,51456)  runbuf f32[64]        (persistent)
//   [51456,52480)  segprod f32[64][4]    (persistent)
// ---------------------------------------------------------------------------
#define LDS_BYTES 52480

__global__ __launch_bounds__(256, 2) void k1(const float* __restrict__ H,
                                             const unsigned short* __restrict__ P_hi,
                                             const unsigned short* __restrict__ P_lo,
                                             float* __restrict__ chunkprod,
                                             float* __restrict__ partial) {
    const int c   = blockIdx.x;
    const int h   = blockIdx.y;
    const int b   = blockIdx.z;
    const int tid = threadIdx.x;
    const int wv  = tid >> 6;
    const int lane = tid & 63;
    const int l31 = lane & 31;
    const int lh  = lane >> 5;
    const int l15 = lane & 15;
    const int q4  = lane >> 4;

    extern __shared__ __align__(16) unsigned char smem[];
    unsigned short* sA_hi = (unsigned short*)(smem);
    unsigned short* sA_lo = (unsigned short*)(smem + 20480);
    unsigned short* sB_hi = (unsigned short*)(smem + 40960);
    unsigned short* sB_lo = (unsigned short*)(smem + 46080);
    unsigned short* wT    = (unsigned short*)(smem);           // [64][264]
    unsigned short* Hh    = (unsigned short*)(smem + 33792);   // [32][264]
    float* runbuf  = (float*)(smem + 51200);
    float* segprod = (float*)(smem + 51456);

    if (tid < 64) runbuf[tid] = 1.0f;

    // partial accumulators: wave wv owns m-range [wv*16, wv*16+16), all 64 d
    f32x4 pacc[4] = {};   // 4 d-tiles of 16

    const int scan_m = tid & 63;   // scan thread mapping: m + segment
    const int scan_g = tid >> 6;

    for (int s = NSUB - 1; s >= 0; --s) {
        const int t_base = c * CHUNK_T + s * SUB_T;

        // ================= score GEMM: 256t x 64m, K=768 ==================
        f32x16 acc[2][2] = {};   // [t-tile 32][m-tile 32]

        for (int kt = 0; kt < 24; ++kt) {
            __syncthreads();
            // stage A: H[t_base..+256][kt*32..+32] -> bf16 hi/lo, pitch 40
#pragma unroll
            for (int j = 0; j < 8; ++j) {
                int slot = tid + j * 256;
                int trow = slot >> 3, k4 = slot & 7;
                const float4 v = *reinterpret_cast<const float4*>(
                    H + (size_t)(b * T_ + t_base + trow) * D_ + kt * 32 + k4 * 4);
                unsigned int u0 = __float_as_uint(v.x), u1 = __float_as_uint(v.y);
                unsigned int u2 = __float_as_uint(v.z), u3 = __float_as_uint(v.w);
                float l0 = v.x - __uint_as_float(u0 & 0xFFFF0000u);
                float l1 = v.y - __uint_as_float(u1 & 0xFFFF0000u);
                float l2 = v.z - __uint_as_float(u2 & 0xFFFF0000u);
                float l3 = v.w - __uint_as_float(u3 & 0xFFFF0000u);
                uint2 hp = {(u0 >> 16) | (u1 & 0xFFFF0000u),
                            (u2 >> 16) | (u3 & 0xFFFF0000u)};
                uint2 lp = {(__float_as_uint(l0) >> 16) | (__float_as_uint(l1) & 0xFFFF0000u),
                            (__float_as_uint(l2) >> 16) | (__float_as_uint(l3) & 0xFFFF0000u)};
                *reinterpret_cast<uint2*>(sA_hi + trow * 40 + k4 * 4) = hp;
                *reinterpret_cast<uint2*>(sA_lo + trow * 40 + k4 * 4) = lp;
            }
            // stage B: P_hi/P_lo[h][m][kt*32..+32] (already bf16), pitch 40
            {
                int m = tid >> 2, k8 = tid & 3;
                size_t src = (size_t)(h * 64 + m) * D_ + kt * 32 + k8 * 8;
                *reinterpret_cast<uint4*>(sB_hi + m * 40 + k8 * 8) =
                    *reinterpret_cast<const uint4*>(P_hi + src);
                *reinterpret_cast<uint4*>(sB_lo + m * 40 + k8 * 8) =
                    *reinterpret_cast<const uint4*>(P_lo + src);
            }
            __syncthreads();

#pragma unroll
            for (int s2 = 0; s2 < 2; ++s2) {
                const int ko = s2 * 16 + lh * 8;
                short8 aH[2], aL[2], bH[2], bL[2];
#pragma unroll
                for (int tt = 0; tt < 2; ++tt) {
                    int row = wv * 64 + tt * 32 + l31;
                    aH[tt] = *reinterpret_cast<const short8*>(sA_hi + row * 40 + ko);
                    aL[tt] = *reinterpret_cast<const short8*>(sA_lo + row * 40 + ko);
                }
#pragma unroll
                for (int mt = 0; mt < 2; ++mt) {
                    int row = mt * 32 + l31;
                    bH[mt] = *reinterpret_cast<const short8*>(sB_hi + row * 40 + ko);
                    bL[mt] = *reinterpret_cast<const short8*>(sB_lo + row * 40 + ko);
                }
#pragma unroll
                for (int tt = 0; tt < 2; ++tt)
#pragma unroll
                    for (int mt = 0; mt < 2; ++mt) {
                        acc[tt][mt] = __builtin_amdgcn_mfma_f32_32x32x16_bf16(
                            aH[tt], bH[mt], acc[tt][mt], 0, 0, 0);
                        acc[tt][mt] = __builtin_amdgcn_mfma_f32_32x32x16_bf16(
                            aH[tt], bL[mt], acc[tt][mt], 0, 0, 0);
                        acc[tt][mt] = __builtin_amdgcn_mfma_f32_32x32x16_bf16(
                            aL[tt], bH[mt], acc[tt][mt], 0, 0, 0);
                    }
            }
        }
        __syncthreads();   // all frag reads of sA/sB done (wT aliases sA)

        // ============ softmax over m, fully in registers ============
        // C/D 32x32 layout: col = l31, row = (r&3) + 8*(r>>2) + 4*lh
#pragma unroll
        for (int tt = 0; tt < 2; ++tt)
#pragma unroll
            for (int r = 0; r < 16; ++r) {
                float mx = fmaxf(acc[tt][0][r], acc[tt][1][r]);
#pragma unroll
                for (int msk = 1; msk <= 16; msk <<= 1)
                    mx = fmaxf(mx, __shfl_xor(mx, msk, 64));
                float e0 = __expf(acc[tt][0][r] - mx);
                float e1 = __expf(acc[tt][1][r] - mx);
                float sm = e0 + e1;
#pragma unroll
                for (int msk = 1; msk <= 16; msk <<= 1)
                    sm += __shfl_xor(sm, msk, 64);
                float inv = 1.0f / sm;
                acc[tt][0][r] = e0 * inv;
                acc[tt][1][r] = e1 * inv;
            }
        // pack w (RTNE bf16) into wT[m][t], pitch 264
#pragma unroll
        for (int tt = 0; tt < 2; ++tt)
#pragma unroll
            for (int mt = 0; mt < 2; ++mt)
#pragma unroll
                for (int bb = 0; bb < 4; ++bb) {
                    unsigned int w0 = rtne_bf16(acc[tt][mt][bb * 4 + 0]);
                    unsigned int w1 = rtne_bf16(acc[tt][mt][bb * 4 + 1]);
                    unsigned int w2 = rtne_bf16(acc[tt][mt][bb * 4 + 2]);
                    unsigned int w3 = rtne_bf16(acc[tt][mt][bb * 4 + 3]);
                    int m = mt * 32 + l31;
                    int t = wv * 64 + tt * 32 + bb * 8 + lh * 4;
                    uint2 pk = {w0 | (w1 << 16), w2 | (w3 << 16)};
                    *reinterpret_cast<uint2*>(wT + m * 264 + t) = pk;
                }
        __syncthreads();

        // ============ segmented suffix gate scan (all 256 threads) ============
        // thread = scan_g*64 + scan_m: segment scan_g of 64 t, column scan_m
        {
            float p = 1.0f;
#pragma unroll
            for (int oct = 0; oct < 8; ++oct) {
                short8 v = *reinterpret_cast<const short8*>(
                    wT + scan_m * 264 + scan_g * 64 + oct * 8);
#pragma unroll
                for (int j = 0; j < 8; ++j) {
                    float w = bf16_to_f((unsigned short)v[j]);
                    p *= fmaf(-ALPHA_, w, 1.0f);
                }
            }
            segprod[(scan_m << 2) + scan_g] = p;
            __syncthreads();
            float R = runbuf[scan_m];
            for (int gg = scan_g + 1; gg < 4; ++gg) R *= segprod[(scan_m << 2) + gg];
            __syncthreads();   // all runbuf reads done before update
#pragma unroll
            for (int oct = 7; oct >= 0; --oct) {
                unsigned short* basep = wT + scan_m * 264 + scan_g * 64 + oct * 8;
                short8 v = *reinterpret_cast<const short8*>(basep);
                short8 o;
#pragma unroll
                for (int j = 7; j >= 0; --j) {
                    float w = bf16_to_f((unsigned short)v[j]);
                    float we = ALPHA_ * w * R;
                    o[j] = (short)rtne_bf16(we);
                    R *= fmaf(-ALPHA_, w, 1.0f);
                }
                *reinterpret_cast<short8*>(basep) = o;
            }
            if (scan_g == 0) runbuf[scan_m] = R;
        }
        __syncthreads();   // w_eff visible

        // ============ partial GEMM: pacc[m][d] += w_eff^T . H_head ============
        for (int hf = 0; hf < 2; ++hf) {
            __syncthreads();   // prior half's Hh reads done
            // stage Hh: H[t_base..+256][h*64+hf*32..+32] -> bf16 [d][t] pitch 264
#pragma unroll
            for (int j = 0; j < 4; ++j) {
                int slot = tid + j * 256;
                int tp = slot >> 3, d4 = slot & 7;
                const float* r0 = H + (size_t)(b * T_ + t_base + 2 * tp) * D_
                                  + h * 64 + hf * 32 + d4 * 4;
                float4 v0 = *reinterpret_cast<const float4*>(r0);
                float4 v1 = *reinterpret_cast<const float4*>(r0 + D_);
                unsigned int c0 = rtne_bf16(v0.x) | (rtne_bf16(v1.x) << 16);
                unsigned int c1 = rtne_bf16(v0.y) | (rtne_bf16(v1.y) << 16);
                unsigned int c2 = rtne_bf16(v0.z) | (rtne_bf16(v1.z) << 16);
                unsigned int c3 = rtne_bf16(v0.w) | (rtne_bf16(v1.w) << 16);
                *reinterpret_cast<unsigned int*>(Hh + (d4 * 4 + 0) * 264 + 2 * tp) = c0;
                *reinterpret_cast<unsigned int*>(Hh + (d4 * 4 + 1) * 264 + 2 * tp) = c1;
                *reinterpret_cast<unsigned int*>(Hh + (d4 * 4 + 2) * 264 + 2 * tp) = c2;
                *reinterpret_cast<unsigned int*>(Hh + (d4 * 4 + 3) * 264 + 2 * tp) = c3;
            }
            __syncthreads();
#pragma unroll
            for (int ks = 0; ks < 8; ++ks) {
                short8 a = *reinterpret_cast<const short8*>(
                    wT + (wv * 16 + l15) * 264 + ks * 32 + q4 * 8);
#pragma unroll
                for (int dt = 0; dt < 2; ++dt) {
                    short8 bb2 = *reinterpret_cast<const short8*>(
                        Hh + (dt * 16 + l15) * 264 + ks * 32 + q4 * 8);
                    pacc[hf * 2 + dt] = __builtin_amdgcn_mfma_f32_16x16x32_bf16(
                        a, bb2, pacc[hf * 2 + dt], 0, 0, 0);
                }
            }
        }
    }

    const int chunkIdx = (b * NH_ + h) * CCH + c;
    if (tid < 64) chunkprod[(size_t)chunkIdx * 64 + tid] = runbuf[tid];
    // D 16x16 layout: row(m) = q4*4+reg, col(d) = l15
#pragma unroll
    for (int dt = 0; dt < 4; ++dt)
#pragma unroll
        for (int rg = 0; rg < 4; ++rg) {
            int m = wv * 16 + q4 * 4 + rg;
            int d = dt * 16 + l15;
            partial[((size_t)chunkIdx * 64 + m) * 64 + d] = pacc[dt][rg];
        }
}

// ---------------------------------------------------------------------------
// Kernel 2: combine chunks with cross-chunk suffix gate products + s0 term.
// ---------------------------------------------------------------------------
__global__ __launch_bounds__(256) void k2(const float* __restrict__ chunkprod,
                                          const float* __restrict__ partial,
                                          const float* __restrict__ s0,
                                          float* __restrict__ out) {
    const int h = blockIdx.x;
    const int b = blockIdx.y;
    const int tid = threadIdx.x;

    __shared__ float Sfx[CCH * M_];
    __shared__ float tot[M_];

    if (tid < M_) {
        const int m = tid;
        float run = 1.0f;
        for (int c = CCH - 1; c >= 0; --c) {
            Sfx[c * M_ + m] = run;
            run *= chunkprod[((size_t)(b * NH_ + h) * CCH + c) * M_ + m];
        }
        tot[m] = run;
    }
    __syncthreads();

    const int m  = tid >> 2;
    const int d0 = (tid & 3) * 16;
    const float tm = tot[m];
    float4 acc[4];
#pragma unroll
    for (int qq = 0; qq < 4; ++qq) {
        const float4 v = *reinterpret_cast<const float4*>(
            s0 + (size_t)m * D_ + h * 64 + d0 + qq * 4);
        acc[qq] = make_float4(v.x * tm, v.y * tm, v.z * tm, v.w * tm);
    }
    for (int c = 0; c < CCH; ++c) {
        const float sv = Sfx[c * M_ + m];
        const size_t base = (((size_t)(b * NH_ + h) * CCH + c) * M_ + m) * HD_ + d0;
#pragma unroll
        for (int qq = 0; qq < 4; ++qq) {
            const float4 p = *reinterpret_cast<const float4*>(partial + base + qq * 4);
            acc[qq].x = fmaf(sv, p.x, acc[qq].x);
            acc[qq].y = fmaf(sv, p.y, acc[qq].y);
            acc[qq].z = fmaf(sv, p.z, acc[qq].z);
            acc[qq].w = fmaf(sv, p.w, acc[qq].w);
        }
    }
    const size_t ob = (size_t)(b * M_ + m) * D_ + h * 64 + d0;
#pragma unroll
    for (int qq = 0; qq < 4; ++qq)
        *reinterpret_cast<float4*>(out + ob + qq * 4) = acc[qq];
}

// ---------------------------------------------------------------------------
extern "C" void kernel_launch(void* const* d_in, const int* in_sizes, int n_in,
                              void* d_out, int out_size, void* d_ws, size_t ws_size,
                              hipStream_t stream) {
    const float* H     = (const float*)d_in[0];
    const float* proto = (const float*)d_in[1];
    const float* W     = (const float*)d_in[2];
    const float* s0    = (const float*)d_in[3];
    float* out = (float*)d_out;

    // ws: P_hi u16[589824] | P_lo u16[589824] | chunkprod f32[49152] | partial f32[3145728]
    unsigned short* P_hi = (unsigned short*)d_ws;
    unsigned short* P_lo = P_hi + 589824;
    float* chunkprod = (float*)((unsigned char*)d_ws + 2359296);
    float* partial   = chunkprod + 49152;

    kP<<<dim3(6, NH_), 256, 0, stream>>>(proto, W, P_hi, P_lo);
    k1<<<dim3(CCH, NH_, B_), 256, LDS_BYTES, stream>>>(H, P_hi, P_lo, chunkprod, partial);
    k2<<<dim3(NH_, B_), 256, 0, stream>>>(chunkprod, partial, s0, out);
}

// Round 3
// 280.412 us; speedup vs baseline: 5.1919x; 1.3207x over previous
//
#include <hip/hip_runtime.h>

#define B_ 8
#define T_ 4096
#define D_ 768
#define NH_ 12
#define HD_ 64
#define M_ 64
#define ALPHA_ 0.1f

#define CCH 16        // chunks over T
#define CHUNK_T 256   // one subtile per block

using half8 = __attribute__((ext_vector_type(8))) _Float16;
using short8 = __attribute__((ext_vector_type(8))) short;
using f32x4 = __attribute__((ext_vector_type(4))) float;

__device__ __forceinline__ unsigned int f2h2(float a, float b) {
    unsigned short ua = __builtin_bit_cast(unsigned short, (_Float16)a);
    unsigned short ub = __builtin_bit_cast(unsigned short, (_Float16)b);
    return (unsigned int)ua | ((unsigned int)ub << 16);
}
__device__ __forceinline__ float h2f(unsigned short u) {
    return (float)__builtin_bit_cast(_Float16, u);
}

// ---------------------------------------------------------------------------
// Kernel 0: P[h,m,e] = (1/8) * sum_i proto[m, h*64+i] * W[h*64+i, e] -> fp16.
// grid (6 e-tiles of 128, 12 heads), 256 threads.
// ---------------------------------------------------------------------------
__global__ __launch_bounds__(256) void kP(const float* __restrict__ proto,
                                          const float* __restrict__ W,
                                          unsigned short* __restrict__ P16) {
    const int et = blockIdx.x;
    const int h  = blockIdx.y;
    const int tid = threadIdx.x;

    __shared__ __align__(16) float Ws[64 * 128];
    __shared__ __align__(16) float Ks[64 * 64];

#pragma unroll
    for (int j = 0; j < 8; ++j) {
        int f = tid + j * 256;
        int i = f >> 5, c4 = f & 31;
        const float4 v = *reinterpret_cast<const float4*>(
            W + (size_t)(h * 64 + i) * D_ + et * 128 + c4 * 4);
        *reinterpret_cast<float4*>(&Ws[i * 128 + c4 * 4]) = v;
    }
#pragma unroll
    for (int j = 0; j < 4; ++j) {
        int f = tid + j * 256;
        int m = f >> 4, i4 = f & 15;
        const float4 v = *reinterpret_cast<const float4*>(
            proto + (size_t)m * D_ + h * 64 + i4 * 4);
        Ks[(i4 * 4 + 0) * 64 + m] = v.x;
        Ks[(i4 * 4 + 1) * 64 + m] = v.y;
        Ks[(i4 * 4 + 2) * 64 + m] = v.z;
        Ks[(i4 * 4 + 3) * 64 + m] = v.w;
    }
    __syncthreads();

    const int m0 = (tid >> 5) * 8;
    const int e0 = (tid & 31) * 4;
    float acc[8][4];
#pragma unroll
    for (int i = 0; i < 8; ++i)
#pragma unroll
        for (int j = 0; j < 4; ++j) acc[i][j] = 0.f;

    for (int i = 0; i < 64; ++i) {
        const float4 bb = *reinterpret_cast<const float4*>(&Ws[i * 128 + e0]);
        const float4 a0 = *reinterpret_cast<const float4*>(&Ks[i * 64 + m0]);
        const float4 a1 = *reinterpret_cast<const float4*>(&Ks[i * 64 + m0 + 4]);
        const float a[8] = {a0.x, a0.y, a0.z, a0.w, a1.x, a1.y, a1.z, a1.w};
#pragma unroll
        for (int mi = 0; mi < 8; ++mi) {
            acc[mi][0] = fmaf(a[mi], bb.x, acc[mi][0]);
            acc[mi][1] = fmaf(a[mi], bb.y, acc[mi][1]);
            acc[mi][2] = fmaf(a[mi], bb.z, acc[mi][2]);
            acc[mi][3] = fmaf(a[mi], bb.w, acc[mi][3]);
        }
    }
#pragma unroll
    for (int mi = 0; mi < 8; ++mi) {
        size_t idx = (size_t)(h * 64 + m0 + mi) * D_ + et * 128 + e0;
        uint2 pk = {f2h2(acc[mi][0] * 0.125f, acc[mi][1] * 0.125f),
                    f2h2(acc[mi][2] * 0.125f, acc[mi][3] * 0.125f)};
        *reinterpret_cast<uint2*>(P16 + idx) = pk;
    }
}

// ---------------------------------------------------------------------------
// Kernel 1: per (chunk=256t, head, batch): fp16 MFMA score GEMM + register
// softmax + segmented suffix scan + fp16 MFMA partial accumulation.
// grid 1536 (1-D, XCD-swizzled), 256 threads, dynamic LDS 51712 B.
//
// LDS map (bytes):
//   [0,36864)      sA  fp16[256][72]    (score phase; pitch 72 halves)
//   [36864,46080)  sB  fp16[64][72]
//   [0,33792)      wT  fp16[64][264]    (aliases sA; softmax/scan/partial)
//   [33792,50688)  Hh  fp16[32][264]    (partial phase; aliases sA tail + sB)
//   [50688,51712)  segprod f32[64][4]   (persistent)
// ---------------------------------------------------------------------------
#define LDS_BYTES 51712

__global__ __launch_bounds__(256, 2) void k1(const float* __restrict__ H,
                                             const unsigned short* __restrict__ P16,
                                             float* __restrict__ chunkprod,
                                             float* __restrict__ partial) {
    const int p = blockIdx.x;
    const int b = p & 7;         // XCD swizzle: batch pinned per XCD,
    const int s = p >> 3;        // 12 heads of one chunk dispatched together
    const int h = s % 12;
    const int c = s / 12;
    const int tid = threadIdx.x;
    const int wv  = tid >> 6;
    const int lane = tid & 63;
    const int l15 = lane & 15;
    const int q4  = lane >> 4;

    extern __shared__ __align__(16) unsigned char smem[];
    unsigned short* sA = (unsigned short*)(smem);
    unsigned short* sB = (unsigned short*)(smem + 36864);
    unsigned short* wT = (unsigned short*)(smem);
    unsigned short* Hh = (unsigned short*)(smem + 33792);
    float* segprod = (float*)(smem + 50688);

    const int t_base = c * CHUNK_T;
    const size_t Hrow0 = (size_t)(b * T_ + t_base) * D_;

    // ================= score GEMM: 256t x 64m, K=768, fp16 =================
    f32x4 acc[4][4] = {};   // wave tile 64t x 64m as 4x4 16x16 tiles

    for (int kt = 0; kt < 12; ++kt) {
        __syncthreads();
        // stage A: H[256t][64k] fp32 -> fp16, pitch 72
        {
            const int row_l = tid >> 4;   // 0..15
            const int kq = tid & 15;
#pragma unroll
            for (int pp = 0; pp < 16; ++pp) {
                int row = pp * 16 + row_l;
                const float4 v = *reinterpret_cast<const float4*>(
                    H + Hrow0 + (size_t)row * D_ + kt * 64 + kq * 4);
                uint2 pk = {f2h2(v.x, v.y), f2h2(v.z, v.w)};
                *reinterpret_cast<uint2*>(sA + row * 72 + kq * 4) = pk;
            }
        }
        // stage B: P16[h][64m][64k], pitch 72
        {
            const int m = tid >> 2, kq = tid & 3;
            const unsigned short* src = P16 + (size_t)(h * 64 + m) * D_ + kt * 64 + kq * 16;
            *reinterpret_cast<uint4*>(sB + m * 72 + kq * 16) =
                *reinterpret_cast<const uint4*>(src);
            *reinterpret_cast<uint4*>(sB + m * 72 + kq * 16 + 8) =
                *reinterpret_cast<const uint4*>(src + 8);
        }
        __syncthreads();
#pragma unroll
        for (int ks = 0; ks < 2; ++ks) {
            half8 af[4], bf[4];
#pragma unroll
            for (int tt = 0; tt < 4; ++tt)
                af[tt] = *reinterpret_cast<const half8*>(
                    sA + (wv * 64 + tt * 16 + l15) * 72 + ks * 32 + q4 * 8);
#pragma unroll
            for (int mt = 0; mt < 4; ++mt)
                bf[mt] = *reinterpret_cast<const half8*>(
                    sB + (mt * 16 + l15) * 72 + ks * 32 + q4 * 8);
#pragma unroll
            for (int tt = 0; tt < 4; ++tt)
#pragma unroll
                for (int mt = 0; mt < 4; ++mt)
                    acc[tt][mt] = __builtin_amdgcn_mfma_f32_16x16x32_f16(
                        af[tt], bf[mt], acc[tt][mt], 0, 0, 0);
        }
    }
    __syncthreads();   // all frag reads done (wT aliases sA)

    // ============ softmax over m in registers ============
    // C/D 16x16: t = tt*16 + q4*4 + rg, m = mt*16 + l15
#pragma unroll
    for (int tt = 0; tt < 4; ++tt)
#pragma unroll
        for (int rg = 0; rg < 4; ++rg) {
            float mx = fmaxf(fmaxf(acc[tt][0][rg], acc[tt][1][rg]),
                             fmaxf(acc[tt][2][rg], acc[tt][3][rg]));
#pragma unroll
            for (int msk = 1; msk <= 8; msk <<= 1)
                mx = fmaxf(mx, __shfl_xor(mx, msk, 64));
            float e0 = __expf(acc[tt][0][rg] - mx);
            float e1 = __expf(acc[tt][1][rg] - mx);
            float e2 = __expf(acc[tt][2][rg] - mx);
            float e3 = __expf(acc[tt][3][rg] - mx);
            float sm = (e0 + e1) + (e2 + e3);
#pragma unroll
            for (int msk = 1; msk <= 8; msk <<= 1)
                sm += __shfl_xor(sm, msk, 64);
            float inv = 1.0f / sm;
            acc[tt][0][rg] = e0 * inv;
            acc[tt][1][rg] = e1 * inv;
            acc[tt][2][rg] = e2 * inv;
            acc[tt][3][rg] = e3 * inv;
        }
    // pack w -> wT[m][t] fp16, pitch 264 (4 consecutive t per lane)
#pragma unroll
    for (int tt = 0; tt < 4; ++tt)
#pragma unroll
        for (int mt = 0; mt < 4; ++mt) {
            uint2 pk = {f2h2(acc[tt][mt][0], acc[tt][mt][1]),
                        f2h2(acc[tt][mt][2], acc[tt][mt][3])};
            *reinterpret_cast<uint2*>(
                wT + (mt * 16 + l15) * 264 + wv * 64 + tt * 16 + q4 * 4) = pk;
        }
    __syncthreads();

    // ============ segmented suffix gate scan (4 segments x 64 t) ============
    {
        const int g = tid >> 6, m = tid & 63;
        unsigned short* rowp = wT + m * 264 + g * 64;
        float pband = 1.0f;
#pragma unroll
        for (int oct = 0; oct < 8; ++oct) {
            short8 v = *reinterpret_cast<const short8*>(rowp + oct * 8);
#pragma unroll
            for (int j = 0; j < 8; ++j) {
                float w = h2f((unsigned short)v[j]);
                pband *= fmaf(-ALPHA_, w, 1.0f);
            }
        }
        segprod[m * 4 + g] = pband;
        __syncthreads();
        float R = 1.0f;
#pragma unroll
        for (int gg = 1; gg < 4; ++gg)
            if (g + gg < 4) R *= segprod[m * 4 + g + gg];
#pragma unroll
        for (int oct = 7; oct >= 0; --oct) {
            short8 v = *reinterpret_cast<const short8*>(rowp + oct * 8);
            short8 o;
#pragma unroll
            for (int j = 7; j >= 0; --j) {
                float w = h2f((unsigned short)v[j]);
                _Float16 we = (_Float16)(ALPHA_ * w * R);
                o[j] = (short)__builtin_bit_cast(unsigned short, we);
                R *= fmaf(-ALPHA_, w, 1.0f);
            }
            *reinterpret_cast<short8*>(rowp + oct * 8) = o;
        }
    }
    __syncthreads();   // w_eff visible

    // ============ partial GEMM: pacc[m][d] += w_eff^T . H_head (fp16) ============
    f32x4 pacc[4] = {};   // wave owns m[wv*16,+16), 4 d-tiles of 16
    for (int hf = 0; hf < 2; ++hf) {
        if (hf) __syncthreads();   // prior half's Hh reads done
        // stage Hh: H[256t][32d] -> fp16 [d][t], pitch 264
        {
            const int dl = tid & 31, tg = tid >> 5;   // 8 t-groups of 32
            const float* src = H + Hrow0 + (size_t)(tg * 32) * D_ + h * 64 + hf * 32 + dl;
            unsigned short* dst = Hh + dl * 264 + tg * 32;
#pragma unroll
            for (int i = 0; i < 32; i += 2) {
                float a  = src[(size_t)i * D_];
                float bb = src[(size_t)(i + 1) * D_];
                *reinterpret_cast<unsigned int*>(dst + i) = f2h2(a, bb);
            }
        }
        __syncthreads();
#pragma unroll
        for (int ks = 0; ks < 8; ++ks) {
            half8 a = *reinterpret_cast<const half8*>(
                wT + (wv * 16 + l15) * 264 + ks * 32 + q4 * 8);
#pragma unroll
            for (int dt = 0; dt < 2; ++dt) {
                half8 bb = *reinterpret_cast<const half8*>(
                    Hh + (dt * 16 + l15) * 264 + ks * 32 + q4 * 8);
                pacc[hf * 2 + dt] = __builtin_amdgcn_mfma_f32_16x16x32_f16(
                    a, bb, pacc[hf * 2 + dt], 0, 0, 0);
            }
        }
    }

    const int chunkIdx = (b * NH_ + h) * CCH + c;
    if (tid < 64)
        chunkprod[(size_t)chunkIdx * 64 + tid] =
            (segprod[tid * 4 + 0] * segprod[tid * 4 + 1]) *
            (segprod[tid * 4 + 2] * segprod[tid * 4 + 3]);
    // D 16x16: m = wv*16 + q4*4 + rg, d = dt*16 + l15
#pragma unroll
    for (int dt = 0; dt < 4; ++dt)
#pragma unroll
        for (int rg = 0; rg < 4; ++rg)
            partial[((size_t)chunkIdx * 64 + wv * 16 + q4 * 4 + rg) * 64 + dt * 16 + l15] =
                pacc[dt][rg];
}

// ---------------------------------------------------------------------------
// Kernel 2: combine 16 chunks with cross-chunk suffix gate products + s0 term.
// ---------------------------------------------------------------------------
__global__ __launch_bounds__(256) void k2(const float* __restrict__ chunkprod,
                                          const float* __restrict__ partial,
                                          const float* __restrict__ s0,
                                          float* __restrict__ out) {
    const int h = blockIdx.x;
    const int b = blockIdx.y;
    const int tid = threadIdx.x;

    __shared__ float Sfx[CCH * M_];
    __shared__ float tot[M_];

    if (tid < M_) {
        const int m = tid;
        float run = 1.0f;
        for (int c = CCH - 1; c >= 0; --c) {
            Sfx[c * M_ + m] = run;
            run *= chunkprod[((size_t)(b * NH_ + h) * CCH + c) * M_ + m];
        }
        tot[m] = run;
    }
    __syncthreads();

    const int m  = tid >> 2;
    const int d0 = (tid & 3) * 16;
    const float tm = tot[m];
    float4 acc[4];
#pragma unroll
    for (int qq = 0; qq < 4; ++qq) {
        const float4 v = *reinterpret_cast<const float4*>(
            s0 + (size_t)m * D_ + h * 64 + d0 + qq * 4);
        acc[qq] = make_float4(v.x * tm, v.y * tm, v.z * tm, v.w * tm);
    }
    for (int c = 0; c < CCH; ++c) {
        const float sv = Sfx[c * M_ + m];
        const size_t base = (((size_t)(b * NH_ + h) * CCH + c) * M_ + m) * HD_ + d0;
#pragma unroll
        for (int qq = 0; qq < 4; ++qq) {
            const float4 pp = *reinterpret_cast<const float4*>(partial + base + qq * 4);
            acc[qq].x = fmaf(sv, pp.x, acc[qq].x);
            acc[qq].y = fmaf(sv, pp.y, acc[qq].y);
            acc[qq].z = fmaf(sv, pp.z, acc[qq].z);
            acc[qq].w = fmaf(sv, pp.w, acc[qq].w);
        }
    }
    const size_t ob = (size_t)(b * M_ + m) * D_ + h * 64 + d0;
#pragma unroll
    for (int qq = 0; qq < 4; ++qq)
        *reinterpret_cast<float4*>(out + ob + qq * 4) = acc[qq];
}

// ---------------------------------------------------------------------------
extern "C" void kernel_launch(void* const* d_in, const int* in_sizes, int n_in,
                              void* d_out, int out_size, void* d_ws, size_t ws_size,
                              hipStream_t stream) {
    const float* H     = (const float*)d_in[0];
    const float* proto = (const float*)d_in[1];
    const float* W     = (const float*)d_in[2];
    const float* s0    = (const float*)d_in[3];
    float* out = (float*)d_out;

    // ws: P16 u16[589824] | chunkprod f32[98304] | partial f32[6291456]  (~26.7 MB)
    unsigned short* P16 = (unsigned short*)d_ws;
    float* chunkprod = (float*)((unsigned char*)d_ws + 1179648);
    float* partial   = (float*)((unsigned char*)d_ws + 1572864);

    kP<<<dim3(6, NH_), 256, 0, stream>>>(proto, W, P16);
    k1<<<dim3(1536), 256, LDS_BYTES, stream>>>(H, P16, chunkprod, partial);
    k2<<<dim3(NH_, B_), 256, 0, stream>>>(chunkprod, partial, s0, out);
}